// Round 2
// baseline (450.135 us; speedup 1.0000x reference)
//
#include <hip/hip_runtime.h>
#include <math.h>

#define NB 16
#define NL 1024
#define NH 8
#define NE 64
#define NWIN 1024
#define NG 64

__device__ __forceinline__ float wave_sum(float v) {
    #pragma unroll
    for (int off = 32; off > 0; off >>= 1) v += __shfl_xor(v, off, 64);
    return v;
}
__device__ __forceinline__ float wave_max(float v) {
    #pragma unroll
    for (int off = 32; off > 0; off >>= 1) v = fmaxf(v, __shfl_xor(v, off, 64));
    return v;
}

// Kernel A: t[b,h,l] = tanh(x_row[r] . mlp_w[c] + mlp_b[c])
// r = b*1024 + h*128 + l/8, c = l%8  (raw-reshape index mixing)
// One wave per row; mlp_w (8x1024 = 32KB) staged in LDS, read as float4
// (ds_read_b128, stride-1 conflict-free) instead of 4x scalar reads.
__global__ __launch_bounds__(256) void k_tanh_mlp(
    const float* __restrict__ x, const float* __restrict__ mlp_w,
    const float* __restrict__ mlp_b, float* __restrict__ t_out)
{
    __shared__ float4 w_lds[8][NWIN / 4];   // 32 KB
    int tid = threadIdx.x;
    const float4* w4 = (const float4*)mlp_w;
    float4* wl = (float4*)w_lds;
    #pragma unroll
    for (int i = 0; i < 8; ++i)
        wl[tid + 256 * i] = w4[tid + 256 * i];
    __syncthreads();

    int wave = tid >> 6, lane = tid & 63;
    int r = blockIdx.x * 4 + wave;                  // [0, 16384)
    const float4* xr = (const float4*)(x + (size_t)r * NWIN);
    float acc[8] = {0.f,0.f,0.f,0.f,0.f,0.f,0.f,0.f};
    #pragma unroll
    for (int it = 0; it < 4; ++it) {
        float4 xv = xr[it * 64 + lane];
        #pragma unroll
        for (int c = 0; c < 8; ++c) {
            float4 wv = w_lds[c][it * 64 + lane];
            acc[c] += xv.x * wv.x + xv.y * wv.y + xv.z * wv.z + xv.w * wv.w;
        }
    }
    #pragma unroll
    for (int c = 0; c < 8; ++c) acc[c] = wave_sum(acc[c]);
    if (lane == 0) {
        int b = r >> 10, rr = r & 1023;
        int h = rr >> 7, l8 = rr & 127;
        float* dst = t_out + ((b * NH + h) * NL) + l8 * 8;
        #pragma unroll
        for (int c = 0; c < 8; ++c)
            dst[c] = tanhf(acc[c] + mlp_b[c]);
    }
}

// Kernel B: qp[b,h,e] = sum_l max(t,0)*q[b,l,h,e]; qn with min(t,0).
// grid = B*H*8 l-chunks of 128; float4 q loads (lane -> (l_off, e4)).
__global__ __launch_bounds__(256) void k_qpn(
    const float* __restrict__ q, const float* __restrict__ t,
    float* __restrict__ qp, float* __restrict__ qn)
{
    int blk = blockIdx.x;
    int lc = blk & 7;
    int bh = blk >> 3;                // b*8+h
    int b = bh >> 3, h = bh & 7;
    int wave = threadIdx.x >> 6, lane = threadIdx.x & 63;
    int lo = lane >> 4, e4 = lane & 15;
    const float* tb = t + bh * NL;
    float4 accp = make_float4(0.f,0.f,0.f,0.f);
    float4 accn = make_float4(0.f,0.f,0.f,0.f);
    int lbase = lc * 128 + wave * 32;
    #pragma unroll
    for (int i = 0; i < 8; ++i) {
        int l = lbase + i * 4 + lo;
        float tv = tb[l];
        float4 qv = *(const float4*)(q + (((size_t)(b * NL + l)) * NH + h) * NE + e4 * 4);
        float tp = fmaxf(tv, 0.f), tn = fminf(tv, 0.f);
        accp.x = fmaf(tp, qv.x, accp.x); accp.y = fmaf(tp, qv.y, accp.y);
        accp.z = fmaf(tp, qv.z, accp.z); accp.w = fmaf(tp, qv.w, accp.w);
        accn.x = fmaf(tn, qv.x, accn.x); accn.y = fmaf(tn, qv.y, accn.y);
        accn.z = fmaf(tn, qv.z, accn.z); accn.w = fmaf(tn, qv.w, accn.w);
    }
    // reduce over l_off (xor 16, 32)
    #pragma unroll
    for (int off = 16; off <= 32; off <<= 1) {
        accp.x += __shfl_xor(accp.x, off, 64); accp.y += __shfl_xor(accp.y, off, 64);
        accp.z += __shfl_xor(accp.z, off, 64); accp.w += __shfl_xor(accp.w, off, 64);
        accn.x += __shfl_xor(accn.x, off, 64); accn.y += __shfl_xor(accn.y, off, 64);
        accn.z += __shfl_xor(accn.z, off, 64); accn.w += __shfl_xor(accn.w, off, 64);
    }
    __shared__ float redp[4][64], redn[4][64];
    if (lo == 0) {
        *(float4*)&redp[wave][e4 * 4] = accp;
        *(float4*)&redn[wave][e4 * 4] = accn;
    }
    __syncthreads();
    if (threadIdx.x < 64) {
        int e = threadIdx.x;
        atomicAdd(&qp[bh * NE + e], redp[0][e] + redp[1][e] + redp[2][e] + redp[3][e]);
    } else if (threadIdx.x < 128) {
        int e = threadIdx.x - 64;
        atomicAdd(&qn[bh * NE + e], redn[0][e] + redn[1][e] + redn[2][e] + redn[3][e]);
    }
}

// Kernel D: per (b,h,chunk of 128 s), wave owns 32 s end-to-end, NO barriers
// in the main loop. Per s: coalesced k/v row loads (lane=e), shuffle-reduced
// ap/an (broadcast to all lanes), lane switches role to g for softmax, then
// the full 64-e outer-product row accumulates per lane via readlane
// broadcasts of the v register. Finale: LDS-atomic cross-wave reduce + 4096
// global atomics per block.
__global__ __launch_bounds__(256, 4) void k_attn_out(
    const float* __restrict__ keys, const float* __restrict__ values,
    const float* __restrict__ sel_W,
    const float* __restrict__ qp, const float* __restrict__ qn,
    float* __restrict__ out)
{
    __shared__ float red[NE * NG];   // 16 KB
    int blk = blockIdx.x;
    int chunk = blk & 7;
    int bh = blk >> 3;
    int b = bh >> 3, h = bh & 7;
    int wave = threadIdx.x >> 6, lane = threadIdx.x & 63;
    const float scale = 0.125f;      // 1/sqrt(64)

    float qpv = qp[bh * NE + lane];
    float qnv = qn[bh * NE + lane];
    float Wg = sel_W[h * NG + lane];
    float Wp = fmaxf(Wg, 0.f), Wn = fminf(Wg, 0.f);

    float acc[NE];
    #pragma unroll
    for (int j = 0; j < NE; ++j) acc[j] = 0.f;

    int s0 = chunk * 128 + wave * 32;
    #pragma unroll 2
    for (int i = 0; i < 32; ++i) {
        int s = s0 + i;
        size_t base = (((size_t)(b * NL + s)) * NH + h) * NE;
        float kv = keys[base + lane];
        float vv = values[base + lane];
        float ap = wave_sum(kv * qpv);
        float an = wave_sum(kv * qnv);
        // lane role: g
        float logit = scale * (Wp * ap + Wn * an);
        float m = wave_max(logit);
        float p = __expf(logit - m);
        float d = wave_sum(p);
        float sv = p / d;            // series[s][g=lane]
        #pragma unroll
        for (int j = 0; j < NE; ++j) {
            float vj = __uint_as_float(__builtin_amdgcn_readlane(__float_as_uint(vv), j));
            acc[j] = fmaf(vj, sv, acc[j]);
        }
    }

    // finale: cross-wave reduce in LDS, then global atomics
    #pragma unroll
    for (int j = 0; j < 16; ++j) red[threadIdx.x * 16 + j] = 0.f;
    __syncthreads();
    #pragma unroll
    for (int e = 0; e < NE; ++e)
        atomicAdd(&red[e * NG + lane], acc[e]);
    __syncthreads();
    float* outb = out + (size_t)b * (NE * NH * NG) + (size_t)h * NG;
    #pragma unroll
    for (int j = 0; j < 16; ++j) {
        int idx = threadIdx.x * 16 + j;
        int e = idx >> 6, g = idx & 63;
        atomicAdd(&outb[(size_t)e * (NH * NG) + g], red[idx]);
    }
}

extern "C" void kernel_launch(void* const* d_in, const int* in_sizes, int n_in,
                              void* d_out, int out_size, void* d_ws, size_t ws_size,
                              hipStream_t stream) {
    (void)in_sizes; (void)n_in; (void)ws_size;
    const float* queries = (const float*)d_in[0];
    const float* keys    = (const float*)d_in[1];
    const float* values  = (const float*)d_in[2];
    const float* x       = (const float*)d_in[3];
    const float* mlp_w   = (const float*)d_in[4];
    const float* mlp_b   = (const float*)d_in[5];
    const float* sel_W   = (const float*)d_in[6];
    float* out = (float*)d_out;

    // ws layout (floats): t[131072] | qp[8192] | qn[8192]
    float* t_ws = (float*)d_ws;
    float* qp_ws = t_ws + NB * NH * NL;
    float* qn_ws = qp_ws + NB * NH * NE;

    hipMemsetAsync(out, 0, (size_t)out_size * sizeof(float), stream);
    hipMemsetAsync(qp_ws, 0, (size_t)2 * NB * NH * NE * sizeof(float), stream);

    k_tanh_mlp<<<dim3(NB * NL / 4), dim3(256), 0, stream>>>(x, mlp_w, mlp_b, t_ws);
    k_qpn<<<dim3(NB * NH * 8), dim3(256), 0, stream>>>(queries, t_ws, qp_ws, qn_ws);
    k_attn_out<<<dim3(NB * NH * 8), dim3(256), 0, stream>>>(keys, values, sel_W,
                                                            qp_ws, qn_ws, out);
}

// Round 3
// 208.755 us; speedup vs baseline: 2.1563x; 2.1563x over previous
//
#include <hip/hip_runtime.h>
#include <math.h>

#define NB 16
#define NL 1024
#define NH 8
#define NE 64
#define NWIN 1024
#define NG 64

#define SCH 256     // s-chunk per block in k_attn_out
#define VROW 264    // bf16 row stride: multiple of 8 (16B b128 alignment), dw-stride 132 (%32==4)

typedef __attribute__((ext_vector_type(8))) short short8;
typedef __attribute__((ext_vector_type(4))) float floatx4;

__device__ __forceinline__ float wave_sum(float v) {
    #pragma unroll
    for (int off = 32; off > 0; off >>= 1) v += __shfl_xor(v, off, 64);
    return v;
}

__device__ __forceinline__ short f2bf(float x) {
    unsigned u = __float_as_uint(x);
    u += 0x7fffu + ((u >> 16) & 1u);   // round-to-nearest-even
    return (short)(u >> 16);
}

// Kernel A: t[b,h,l] = tanh(x_row[r] . mlp_w[c] + mlp_b[c])
// r = b*1024 + h*128 + l/8, c = l%8  (raw-reshape index mixing). f32 (logit
// path precision — bf16 here perturbs softmax logits by ~0.1-0.3, unsafe).
__global__ __launch_bounds__(256) void k_tanh_mlp(
    const float* __restrict__ x, const float* __restrict__ mlp_w,
    const float* __restrict__ mlp_b, float* __restrict__ t_out)
{
    __shared__ float4 w_lds[8][NWIN / 4];   // 32 KB
    int tid = threadIdx.x;
    const float4* w4 = (const float4*)mlp_w;
    float4* wl = (float4*)w_lds;
    #pragma unroll
    for (int i = 0; i < 8; ++i)
        wl[tid + 256 * i] = w4[tid + 256 * i];
    __syncthreads();

    int wave = tid >> 6, lane = tid & 63;
    int r = blockIdx.x * 4 + wave;                  // [0, 16384)
    const float4* xr = (const float4*)(x + (size_t)r * NWIN);
    float acc[8] = {0.f,0.f,0.f,0.f,0.f,0.f,0.f,0.f};
    #pragma unroll
    for (int it = 0; it < 4; ++it) {
        float4 xv = xr[it * 64 + lane];
        #pragma unroll
        for (int c = 0; c < 8; ++c) {
            float4 wv = w_lds[c][it * 64 + lane];
            acc[c] += xv.x * wv.x + xv.y * wv.y + xv.z * wv.z + xv.w * wv.w;
        }
    }
    #pragma unroll
    for (int c = 0; c < 8; ++c) acc[c] = wave_sum(acc[c]);
    if (lane == 0) {
        int b = r >> 10, rr = r & 1023;
        int h = rr >> 7, l8 = rr & 127;
        float* dst = t_out + ((b * NH + h) * NL) + l8 * 8;
        #pragma unroll
        for (int c = 0; c < 8; ++c)
            dst[c] = tanhf(acc[c] + mlp_b[c]);
    }
}

// Kernel B: qp[b,h,e] = sum_l max(t,0)*q[b,l,h,e]; qn with min(t,0). f32.
__global__ __launch_bounds__(256) void k_qpn(
    const float* __restrict__ q, const float* __restrict__ t,
    float* __restrict__ qp, float* __restrict__ qn)
{
    int blk = blockIdx.x;
    int lc = blk & 7;
    int bh = blk >> 3;                // b*8+h
    int b = bh >> 3, h = bh & 7;
    int wave = threadIdx.x >> 6, lane = threadIdx.x & 63;
    int lo = lane >> 4, e4 = lane & 15;
    const float* tb = t + bh * NL;
    float4 accp = make_float4(0.f,0.f,0.f,0.f);
    float4 accn = make_float4(0.f,0.f,0.f,0.f);
    int lbase = lc * 128 + wave * 32;
    #pragma unroll
    for (int i = 0; i < 8; ++i) {
        int l = lbase + i * 4 + lo;
        float tv = tb[l];
        float4 qv = *(const float4*)(q + (((size_t)(b * NL + l)) * NH + h) * NE + e4 * 4);
        float tp = fmaxf(tv, 0.f), tn = fminf(tv, 0.f);
        accp.x = fmaf(tp, qv.x, accp.x); accp.y = fmaf(tp, qv.y, accp.y);
        accp.z = fmaf(tp, qv.z, accp.z); accp.w = fmaf(tp, qv.w, accp.w);
        accn.x = fmaf(tn, qv.x, accn.x); accn.y = fmaf(tn, qv.y, accn.y);
        accn.z = fmaf(tn, qv.z, accn.z); accn.w = fmaf(tn, qv.w, accn.w);
    }
    #pragma unroll
    for (int off = 16; off <= 32; off <<= 1) {
        accp.x += __shfl_xor(accp.x, off, 64); accp.y += __shfl_xor(accp.y, off, 64);
        accp.z += __shfl_xor(accp.z, off, 64); accp.w += __shfl_xor(accp.w, off, 64);
        accn.x += __shfl_xor(accn.x, off, 64); accn.y += __shfl_xor(accn.y, off, 64);
        accn.z += __shfl_xor(accn.z, off, 64); accn.w += __shfl_xor(accn.w, off, 64);
    }
    __shared__ float redp[4][64], redn[4][64];
    if (lo == 0) {
        *(float4*)&redp[wave][e4 * 4] = accp;
        *(float4*)&redn[wave][e4 * 4] = accn;
    }
    __syncthreads();
    if (threadIdx.x < 64) {
        int e = threadIdx.x;
        atomicAdd(&qp[bh * NE + e], redp[0][e] + redp[1][e] + redp[2][e] + redp[3][e]);
    } else if (threadIdx.x < 128) {
        int e = threadIdx.x - 64;
        atomicAdd(&qn[bh * NE + e], redn[0][e] + redn[1][e] + redn[2][e] + redn[3][e]);
    }
}

// Kernel D v3: per (b,h, s-chunk of 256). f32 logit path, bf16 MFMA for the
// post-softmax PV contraction V[e,g] += sum_s v[s,e]*series[s,g].
// Phase A: ap/an (float4 loads, 4-round butterfly = 2 shuffles/s) + v->bf16
//          staged transposed in LDS [e][s].
// Phase B: lane=s, zero shuffles: 3 g-loops (max, denom, write p/d bf16 [g][s]).
// Phase C: 32x mfma_f32_16x16x32_bf16 per wave; wave owns e-tile 16w.
//   frag layouts (m89/m120): A[m=lane&15][k=(lane>>4)*8+j],
//   B[k=(lane>>4)*8+j][n=lane&15], D[row=(lane>>4)*4+r][col=lane&15].
// Max 16 acc VGPRs/thread — no spill (round-2 failure mode).
__global__ __launch_bounds__(256) void k_attn_out(
    const float* __restrict__ keys, const float* __restrict__ values,
    const float* __restrict__ sel_W,
    const float* __restrict__ qp, const float* __restrict__ qn,
    float* __restrict__ out)
{
    __shared__ short vb[NE][VROW];     // 33 KB  v bf16, [e][s]
    __shared__ short sb[NG][VROW];     // 33 KB  series bf16, [g][s]
    __shared__ float ap_l[SCH], an_l[SCH];
    __shared__ float2 wpn[NG];         // {wp*scale, wn*scale}

    int blk = blockIdx.x;
    int chunk = blk & 3;
    int bh = blk >> 2;
    int b = bh >> 3, h = bh & 7;
    int tid = threadIdx.x;
    int w = tid >> 6, lane = tid & 63;
    const float scale = 0.125f;        // 1/sqrt(64)

    if (tid < NG) {
        float W = sel_W[h * NG + tid];
        wpn[tid] = make_float2(fmaxf(W, 0.f) * scale, fminf(W, 0.f) * scale);
    }

    int c = lane & 15, sq = lane >> 4;
    const float4 qp4 = *(const float4*)(qp + bh * NE + c * 4);
    const float4 qn4 = *(const float4*)(qn + bh * NE + c * 4);

    // ---- phase A-k: ap/an for this wave's 64 s (4 s per pass) ----
    #pragma unroll 4
    for (int p_ = 0; p_ < 16; ++p_) {
        int sl = w * 64 + p_ * 4 + sq;            // s_loc in chunk
        int s = chunk * SCH + sl;
        float4 kv = *(const float4*)(keys + (((size_t)(b * NL + s)) * NH + h) * NE + c * 4);
        float pp = kv.x * qp4.x + kv.y * qp4.y + kv.z * qp4.z + kv.w * qp4.w;
        float pn = kv.x * qn4.x + kv.y * qn4.y + kv.z * qn4.z + kv.w * qn4.w;
        #pragma unroll
        for (int m_ = 1; m_ <= 8; m_ <<= 1) {     // reduce across 16 e-lanes
            pp += __shfl_xor(pp, m_, 64);
            pn += __shfl_xor(pn, m_, 64);
        }
        if (c == 0) { ap_l[sl] = pp; an_l[sl] = pn; }
    }

    // ---- phase A-v: v rows -> bf16 -> LDS [e][s] ----
    #pragma unroll 4
    for (int i = 0; i < 64; ++i) {
        int sl = w * 64 + i;
        int s = chunk * SCH + sl;
        float v = values[(((size_t)(b * NL + s)) * NH + h) * NE + lane];
        vb[lane][sl] = f2bf(v);
    }
    __syncthreads();

    // ---- phase B: lane = s, softmax over g, normalized p -> bf16 [g][s] ----
    {
        int sl = w * 64 + lane;
        float ap = ap_l[sl], an = an_l[sl];
        float m = -INFINITY;
        #pragma unroll 8
        for (int g = 0; g < NG; ++g) {
            float2 wv = wpn[g];
            float lg = wv.x * ap + wv.y * an;
            m = fmaxf(m, lg);
        }
        float d = 0.f;
        #pragma unroll 8
        for (int g = 0; g < NG; ++g) {
            float2 wv = wpn[g];
            float lg = wv.x * ap + wv.y * an;
            d += __expf(lg - m);
        }
        float inv = 1.0f / d;
        #pragma unroll 8
        for (int g = 0; g < NG; ++g) {
            float2 wv = wpn[g];
            float lg = wv.x * ap + wv.y * an;
            sb[g][sl] = f2bf(__expf(lg - m) * inv);
        }
    }
    __syncthreads();

    // ---- phase C: MFMA. wave owns e-rows [16w, 16w+16) ----
    floatx4 acc[4] = {{0.f,0.f,0.f,0.f},{0.f,0.f,0.f,0.f},
                      {0.f,0.f,0.f,0.f},{0.f,0.f,0.f,0.f}};
    int kq = lane >> 4;                 // k-quad
    #pragma unroll
    for (int ks = 0; ks < SCH / 32; ++ks) {
        short8 av = *(const short8*)&vb[16 * w + c][ks * 32 + kq * 8];
        #pragma unroll
        for (int n = 0; n < 4; ++n) {
            short8 bv = *(const short8*)&sb[16 * n + c][ks * 32 + kq * 8];
            acc[n] = __builtin_amdgcn_mfma_f32_16x16x32_bf16(av, bv, acc[n], 0, 0, 0);
        }
    }

    // epilogue: D[row=(lane>>4)*4+r][col=lane&15]; 4 chunk-blocks accumulate.
    #pragma unroll
    for (int n = 0; n < 4; ++n) {
        #pragma unroll
        for (int r = 0; r < 4; ++r) {
            int e = 16 * w + kq * 4 + r;
            int g = 16 * n + c;
            atomicAdd(&out[((size_t)(b * NE + e) * NH + h) * NG + g], acc[n][r]);
        }
    }
}

extern "C" void kernel_launch(void* const* d_in, const int* in_sizes, int n_in,
                              void* d_out, int out_size, void* d_ws, size_t ws_size,
                              hipStream_t stream) {
    (void)in_sizes; (void)n_in; (void)ws_size;
    const float* queries = (const float*)d_in[0];
    const float* keys    = (const float*)d_in[1];
    const float* values  = (const float*)d_in[2];
    const float* x       = (const float*)d_in[3];
    const float* mlp_w   = (const float*)d_in[4];
    const float* mlp_b   = (const float*)d_in[5];
    const float* sel_W   = (const float*)d_in[6];
    float* out = (float*)d_out;

    // ws layout (floats): t[131072] | qp[8192] | qn[8192]
    float* t_ws = (float*)d_ws;
    float* qp_ws = t_ws + NB * NH * NL;
    float* qn_ws = qp_ws + NB * NH * NE;

    hipMemsetAsync(out, 0, (size_t)out_size * sizeof(float), stream);
    hipMemsetAsync(qp_ws, 0, (size_t)2 * NB * NH * NE * sizeof(float), stream);

    k_tanh_mlp<<<dim3(NB * NL / 4), dim3(256), 0, stream>>>(x, mlp_w, mlp_b, t_ws);
    k_qpn<<<dim3(NB * NH * 8), dim3(256), 0, stream>>>(queries, t_ws, qp_ws, qn_ws);
    k_attn_out<<<dim3(NB * NH * 4), dim3(256), 0, stream>>>(keys, values, sel_W,
                                                            qp_ws, qn_ws, out);
}

// Round 4
// 199.194 us; speedup vs baseline: 2.2598x; 1.0480x over previous
//
#include <hip/hip_runtime.h>
#include <math.h>

#define NB 16
#define NL 1024
#define NH 8
#define NE 64
#define NWIN 1024
#define NG 64

#define SCH 128     // s-chunk per block in k_attn_out
#define SROW 136    // sb row stride in shorts (16B-aligned: 136*2=272 ≡ 0 mod 16)

typedef __attribute__((ext_vector_type(8))) short short8;
typedef __attribute__((ext_vector_type(4))) float floatx4;

__device__ __forceinline__ short f2bf(float x) {
    unsigned u = __float_as_uint(x);
    u += 0x7fffu + ((u >> 16) & 1u);   // round-to-nearest-even
    return (short)(u >> 16);
}
__device__ __forceinline__ float dot4(float4 a, float4 b) {
    return fmaf(a.x, b.x, fmaf(a.y, b.y, fmaf(a.z, b.z, a.w * b.w)));
}

// Fused kernel: tanh-MLP (t stays in LDS) + qp/qn reduction.
// Block = (b, h, quarter q of the l-range). t[b,h,l], l = l8*8+c with
// l8 = h*128-row mixing (raw reshape), handled per-wave: wave w computes rows
// l8 = qq*32 + w*8 + [0,8), i.e. l in [qq*256 + w*64, +64) — exactly the l
// range its qpn phase needs... (block handles l in [qq*256, qq*256+256)).
__global__ __launch_bounds__(256) void k_sel_q(
    const float* __restrict__ x, const float* __restrict__ mlp_w,
    const float* __restrict__ mlp_b, const float* __restrict__ q,
    float* __restrict__ qp, float* __restrict__ qn)
{
    __shared__ float4 w_lds[8][NWIN / 4];   // 32 KB
    __shared__ float t_lds[256];
    __shared__ float redp[4][64], redn[4][64];

    int tid = threadIdx.x;
    int blk = blockIdx.x;
    int qq = blk & 3, bh = blk >> 2;
    int b = bh >> 3, h = bh & 7;
    int w = tid >> 6, lane = tid & 63;

    const float4* w4 = (const float4*)mlp_w;
    float4* wl = (float4*)w_lds;
    #pragma unroll
    for (int i = 0; i < 8; ++i)
        wl[tid + 256 * i] = w4[tid + 256 * i];
    __syncthreads();

    // ---- phase 1: tanh-MLP for this block's 32 rows (8 per wave) ----
    float4 keep03 = make_float4(0,0,0,0), keep47 = make_float4(0,0,0,0);
    int r0 = b * 1024 + h * 128 + qq * 32 + w * 8;
    for (int j = 0; j < 8; ++j) {
        const float4* xr = (const float4*)(x + (size_t)(r0 + j) * NWIN);
        float4 a03 = make_float4(0,0,0,0), a47 = make_float4(0,0,0,0);
        #pragma unroll
        for (int it = 0; it < 4; ++it) {
            float4 xv = xr[it * 64 + lane];
            a03.x += dot4(xv, w_lds[0][it * 64 + lane]);
            a03.y += dot4(xv, w_lds[1][it * 64 + lane]);
            a03.z += dot4(xv, w_lds[2][it * 64 + lane]);
            a03.w += dot4(xv, w_lds[3][it * 64 + lane]);
            a47.x += dot4(xv, w_lds[4][it * 64 + lane]);
            a47.y += dot4(xv, w_lds[5][it * 64 + lane]);
            a47.z += dot4(xv, w_lds[6][it * 64 + lane]);
            a47.w += dot4(xv, w_lds[7][it * 64 + lane]);
        }
        #pragma unroll
        for (int off = 1; off < 64; off <<= 1) {
            a03.x += __shfl_xor(a03.x, off, 64);
            a03.y += __shfl_xor(a03.y, off, 64);
            a03.z += __shfl_xor(a03.z, off, 64);
            a03.w += __shfl_xor(a03.w, off, 64);
            a47.x += __shfl_xor(a47.x, off, 64);
            a47.y += __shfl_xor(a47.y, off, 64);
            a47.z += __shfl_xor(a47.z, off, 64);
            a47.w += __shfl_xor(a47.w, off, 64);
        }
        if (lane == j) { keep03 = a03; keep47 = a47; }
    }
    if (lane < 8) {
        float4 b03 = *(const float4*)mlp_b;
        float4 b47 = *(const float4*)(mlp_b + 4);
        float4 t03, t47;
        t03.x = tanhf(keep03.x + b03.x); t03.y = tanhf(keep03.y + b03.y);
        t03.z = tanhf(keep03.z + b03.z); t03.w = tanhf(keep03.w + b03.w);
        t47.x = tanhf(keep47.x + b47.x); t47.y = tanhf(keep47.y + b47.y);
        t47.z = tanhf(keep47.z + b47.z); t47.w = tanhf(keep47.w + b47.w);
        *(float4*)&t_lds[w * 64 + lane * 8]     = t03;
        *(float4*)&t_lds[w * 64 + lane * 8 + 4] = t47;
    }
    __syncthreads();

    // ---- phase 2: qp/qn partial over l in [qq*256, qq*256+256) ----
    int lo = lane >> 4, e4 = lane & 15;
    float4 accp = make_float4(0,0,0,0), accn = make_float4(0,0,0,0);
    #pragma unroll 4
    for (int i = 0; i < 16; ++i) {
        int l_loc = w * 64 + i * 4 + lo;
        float tv = t_lds[l_loc];
        int l = qq * 256 + l_loc;
        float4 qv = *(const float4*)(q + (((size_t)(b * NL + l)) * NH + h) * NE + e4 * 4);
        float tp = fmaxf(tv, 0.f), tn = fminf(tv, 0.f);
        accp.x = fmaf(tp, qv.x, accp.x); accp.y = fmaf(tp, qv.y, accp.y);
        accp.z = fmaf(tp, qv.z, accp.z); accp.w = fmaf(tp, qv.w, accp.w);
        accn.x = fmaf(tn, qv.x, accn.x); accn.y = fmaf(tn, qv.y, accn.y);
        accn.z = fmaf(tn, qv.z, accn.z); accn.w = fmaf(tn, qv.w, accn.w);
    }
    #pragma unroll
    for (int off = 16; off <= 32; off <<= 1) {
        accp.x += __shfl_xor(accp.x, off, 64); accp.y += __shfl_xor(accp.y, off, 64);
        accp.z += __shfl_xor(accp.z, off, 64); accp.w += __shfl_xor(accp.w, off, 64);
        accn.x += __shfl_xor(accn.x, off, 64); accn.y += __shfl_xor(accn.y, off, 64);
        accn.z += __shfl_xor(accn.z, off, 64); accn.w += __shfl_xor(accn.w, off, 64);
    }
    if (lo == 0) {
        *(float4*)&redp[w][e4 * 4] = accp;
        *(float4*)&redn[w][e4 * 4] = accn;
    }
    __syncthreads();
    if (tid < 64) {
        atomicAdd(&qp[bh * NE + tid], redp[0][tid] + redp[1][tid] + redp[2][tid] + redp[3][tid]);
    } else if (tid < 128) {
        int e = tid - 64;
        atomicAdd(&qn[bh * NE + e], redn[0][e] + redn[1][e] + redn[2][e] + redn[3][e]);
    }
}

// Attention kernel v4: per (b, h, s-chunk of 128). No v-transpose LDS tile:
// MFMA A-fragments (v, bf16) are gathered straight from global (64B-line
// coalesced, each element read once) — round-3's 8-way-conflicted b16 column
// writes are gone, LDS drops to ~22 KB -> 4+ blocks/CU.
__global__ __launch_bounds__(256, 4) void k_attn_out(
    const float* __restrict__ keys, const float* __restrict__ values,
    const float* __restrict__ sel_W,
    const float* __restrict__ qp, const float* __restrict__ qn,
    float* __restrict__ out)
{
    __shared__ short sb[NG][SROW];          // 17 KB  series bf16, [g][s]
    __shared__ float ap_l[SCH], an_l[SCH];
    __shared__ float2 wpn[NG];
    __shared__ float mx2[2][SCH], dn2[2][SCH];

    int tid = threadIdx.x, blk = blockIdx.x;
    int chunk = blk & 7, bh = blk >> 3;
    int b = bh >> 3, h = bh & 7;
    int w = tid >> 6, lane = tid & 63;
    int c = lane & 15, sq = lane >> 4;
    const float scale = 0.125f;             // 1/sqrt(64)

    if (tid < NG) {
        float W = sel_W[h * NG + tid];
        wpn[tid] = make_float2(fmaxf(W, 0.f) * scale, fminf(W, 0.f) * scale);
    }

    const float4 qp4 = *(const float4*)(qp + bh * NE + c * 4);
    const float4 qn4 = *(const float4*)(qn + bh * NE + c * 4);
    int s0 = chunk * SCH;

    // ---- phase A: ap/an (wave owns 32 s) ----
    #pragma unroll
    for (int p = 0; p < 8; ++p) {
        int sl = w * 32 + p * 4 + sq;
        float4 kv = *(const float4*)(keys + (((size_t)(b * NL + s0 + sl)) * NH + h) * NE + c * 4);
        float pp = dot4(kv, qp4);
        float pn = dot4(kv, qn4);
        #pragma unroll
        for (int m_ = 1; m_ <= 8; m_ <<= 1) {
            pp += __shfl_xor(pp, m_, 64);
            pn += __shfl_xor(pn, m_, 64);
        }
        if (c == 0) { ap_l[sl] = pp; an_l[sl] = pn; }
    }
    __syncthreads();

    // ---- phase B: softmax over g, split g-range across thread halves ----
    {
        int s_ = tid & 127, gh = tid >> 7, g0 = gh * 32;
        float ap = ap_l[s_], an = an_l[s_];
        float m = -1e30f;
        #pragma unroll 8
        for (int g = 0; g < 32; ++g) {
            float2 wv = wpn[g0 + g];
            m = fmaxf(m, fmaf(wv.x, ap, wv.y * an));
        }
        mx2[gh][s_] = m;
        __syncthreads();
        m = fmaxf(mx2[0][s_], mx2[1][s_]);
        float d = 0.f;
        #pragma unroll 8
        for (int g = 0; g < 32; ++g) {
            float2 wv = wpn[g0 + g];
            d += __expf(fmaf(wv.x, ap, wv.y * an) - m);
        }
        dn2[gh][s_] = d;
        __syncthreads();
        float inv = 1.0f / (dn2[0][s_] + dn2[1][s_]);
        #pragma unroll 8
        for (int g = 0; g < 32; ++g) {
            float2 wv = wpn[g0 + g];
            sb[g0 + g][s_] = f2bf(__expf(fmaf(wv.x, ap, wv.y * an) - m) * inv);
        }
    }
    __syncthreads();

    // ---- phase C: MFMA, wave owns e-tile [16w, 16w+16) ----
    floatx4 acc[4] = {{0.f,0.f,0.f,0.f},{0.f,0.f,0.f,0.f},
                      {0.f,0.f,0.f,0.f},{0.f,0.f,0.f,0.f}};
    const float* vbase = values + (((size_t)(b * NL + s0)) * NH + h) * NE + 16 * w + c;
    #pragma unroll
    for (int ks = 0; ks < 4; ++ks) {
        float a[8];
        #pragma unroll
        for (int j = 0; j < 8; ++j)
            a[j] = vbase[(size_t)(ks * 32 + sq * 8 + j) * (NH * NE)];
        short8 av;
        #pragma unroll
        for (int j = 0; j < 8; ++j) av[j] = f2bf(a[j]);
        #pragma unroll
        for (int n = 0; n < 4; ++n) {
            short8 bv = *(const short8*)&sb[16 * n + c][ks * 32 + sq * 8];
            acc[n] = __builtin_amdgcn_mfma_f32_16x16x32_bf16(av, bv, acc[n], 0, 0, 0);
        }
    }

    // epilogue: D[row=sq*4+r][col=c]; 8 s-chunk blocks accumulate per (b,h).
    #pragma unroll
    for (int n = 0; n < 4; ++n) {
        #pragma unroll
        for (int r = 0; r < 4; ++r) {
            int e = 16 * w + sq * 4 + r;
            int g = 16 * n + c;
            atomicAdd(&out[((size_t)(b * NE + e) * NH + h) * NG + g], acc[n][r]);
        }
    }
}

extern "C" void kernel_launch(void* const* d_in, const int* in_sizes, int n_in,
                              void* d_out, int out_size, void* d_ws, size_t ws_size,
                              hipStream_t stream) {
    (void)in_sizes; (void)n_in; (void)ws_size;
    const float* queries = (const float*)d_in[0];
    const float* keys    = (const float*)d_in[1];
    const float* values  = (const float*)d_in[2];
    const float* x       = (const float*)d_in[3];
    const float* mlp_w   = (const float*)d_in[4];
    const float* mlp_b   = (const float*)d_in[5];
    const float* sel_W   = (const float*)d_in[6];
    float* out = (float*)d_out;

    // ws layout (floats): qp[8192] | qn[8192]
    float* qp_ws = (float*)d_ws;
    float* qn_ws = qp_ws + NB * NH * NE;

    hipMemsetAsync(out, 0, (size_t)out_size * sizeof(float), stream);
    hipMemsetAsync(qp_ws, 0, (size_t)2 * NB * NH * NE * sizeof(float), stream);

    k_sel_q<<<dim3(NB * NH * 4), dim3(256), 0, stream>>>(x, mlp_w, mlp_b,
                                                          queries, qp_ws, qn_ws);
    k_attn_out<<<dim3(NB * NH * 8), dim3(256), 0, stream>>>(keys, values, sel_W,
                                                            qp_ws, qn_ws, out);
}